// Round 1
// baseline (115.658 us; speedup 1.0000x reference)
//
#include <hip/hip_runtime.h>
#include <cstdint>
#include <cstddef>

#define E_DIM 1024
#define PD 64            // proj dim
#define NP 128           // 2*proj dim
#define B_DIM 8
#define S_DIM 2048
#define M_TOT (B_DIM * S_DIM)   // 16384

// ---------------- K1: GEMM qk[m][p] = sum_k A[m][k] * W[p][k] + bias[p] ----------------
// A is context viewed as (S*B, E) row-major; row m = s*B + b.
#define BM 64
#define BK 32
#define SA 68    // BM + 4 pad (keeps 16B alignment, avoids bank conflicts on scatter)
#define SB 132   // NP + 4 pad

__global__ __launch_bounds__(256) void gemm_qk(const float* __restrict__ A,
                                               const float* __restrict__ W,
                                               const float* __restrict__ bias,
                                               float* __restrict__ qk) {
    __shared__ float As[BK * SA];
    __shared__ float Bs[BK * SB];
    const int tid = threadIdx.x;
    const int m0 = blockIdx.x * BM;
    const int ty = tid >> 4;      // 0..15 -> rows ty*4..+4
    const int tx = tid & 15;      // 0..15 -> cols tx*8..+8

    float bvals[8];
#pragma unroll
    for (int c = 0; c < 8; ++c) bvals[c] = bias[tx * 8 + c];

    float acc[4][8];
#pragma unroll
    for (int r = 0; r < 4; ++r)
#pragma unroll
        for (int c = 0; c < 8; ++c) acc[r][c] = 0.f;

    const int lrow = tid >> 3;        // 0..31
    const int lk = (tid & 7) * 4;     // 0,4,...,28

    for (int kc = 0; kc < E_DIM; kc += BK) {
        __syncthreads();
        // stage A tile (64 rows x 32 k), transposed into As[k][row]
#pragma unroll
        for (int p = 0; p < 2; ++p) {
            const int row = lrow + p * 32;
            const float4 a = *(const float4*)&A[(size_t)(m0 + row) * E_DIM + kc + lk];
            As[(lk + 0) * SA + row] = a.x;
            As[(lk + 1) * SA + row] = a.y;
            As[(lk + 2) * SA + row] = a.z;
            As[(lk + 3) * SA + row] = a.w;
        }
        // stage W tile (128 rows x 32 k), transposed into Bs[k][p]
#pragma unroll
        for (int p = 0; p < 4; ++p) {
            const int pr = lrow + p * 32;
            const float4 w = *(const float4*)&W[(size_t)pr * E_DIM + kc + lk];
            Bs[(lk + 0) * SB + pr] = w.x;
            Bs[(lk + 1) * SB + pr] = w.y;
            Bs[(lk + 2) * SB + pr] = w.z;
            Bs[(lk + 3) * SB + pr] = w.w;
        }
        __syncthreads();
#pragma unroll
        for (int k = 0; k < BK; ++k) {
            const float4 a4 = *(const float4*)&As[k * SA + ty * 4];
            const float4 b0 = *(const float4*)&Bs[k * SB + tx * 8];
            const float4 b1 = *(const float4*)&Bs[k * SB + tx * 8 + 4];
            const float av[4] = {a4.x, a4.y, a4.z, a4.w};
            const float bv[8] = {b0.x, b0.y, b0.z, b0.w, b1.x, b1.y, b1.z, b1.w};
#pragma unroll
            for (int r = 0; r < 4; ++r)
#pragma unroll
                for (int c = 0; c < 8; ++c) acc[r][c] += av[r] * bv[c];
        }
    }

#pragma unroll
    for (int r = 0; r < 4; ++r) {
        const size_t m = (size_t)m0 + ty * 4 + r;
        float4 o0, o1;
        o0.x = acc[r][0] + bvals[0]; o0.y = acc[r][1] + bvals[1];
        o0.z = acc[r][2] + bvals[2]; o0.w = acc[r][3] + bvals[3];
        o1.x = acc[r][4] + bvals[4]; o1.y = acc[r][5] + bvals[5];
        o1.z = acc[r][6] + bvals[6]; o1.w = acc[r][7] + bvals[7];
        *(float4*)&qk[m * NP + tx * 8] = o0;
        *(float4*)&qk[m * NP + tx * 8 + 4] = o1;
    }
}

// ---------------- K2: neighbor scores + 2-way softmax -> p0,p1 (indexed b*S+s) ----------------
__global__ __launch_bounds__(256) void neighbor_probs(const float* __restrict__ qk,
                                                      float* __restrict__ p0,
                                                      float* __restrict__ p1) {
    const int wid = blockIdx.x * 4 + (threadIdx.x >> 6);  // position index m = s*B+b
    const int lane = threadIdx.x & 63;
    const int m = wid;
    const int s = m >> 3;   // / B_DIM
    const int b = m & 7;    // % B_DIM

    const float q = qk[(size_t)m * NP + lane];
    const float kn = (s < S_DIM - 1) ? qk[(size_t)(m + B_DIM) * NP + PD + lane] : 0.f;
    const float kp = (s > 0) ? qk[(size_t)(m - B_DIM) * NP + PD + lane] : 0.f;
    float f = q * kn;   // fwd partial: query[s] . key[s+1]
    float g = q * kp;   // bwd partial: query[s] . key[s-1]
#pragma unroll
    for (int off = 32; off; off >>= 1) {
        f += __shfl_xor(f, off);
        g += __shfl_xor(g, off);
    }
    if (lane == 0) {
        const float s0 = f * (1.f / (float)E_DIM);
        const float s1 = g * (1.f / (float)E_DIM);
        float P0, P1;
        if (s == S_DIM - 1) { P0 = 0.f; P1 = 1.f; }
        else if (s == 0)    { P0 = 1.f; P1 = 0.f; }
        else {
            const float mx = fmaxf(s0, s1);
            const float e0 = __expf(s0 - mx), e1 = __expf(s1 - mx);
            const float inv = 1.f / (e0 + e1);
            P0 = e0 * inv; P1 = e1 * inv;
        }
        p0[b * S_DIM + s] = P0;
        p1[b * S_DIM + s] = P1;
    }
}

// ---------------- K3: combine (with flat roll), neighbor_attn out, log, exclusive scan ----------------
__global__ __launch_bounds__(256) void combine_scan(const float* __restrict__ p0,
                                                    const float* __restrict__ p1,
                                                    const float* __restrict__ prior,
                                                    float* __restrict__ out_na,
                                                    float* __restrict__ cs) {
    const int b = blockIdx.x;
    const int tid = threadIdx.x;
    __shared__ float sh[256];

    const int base = b * S_DIM + tid * 8;
    float incl[8];
    float run = 0.f;
#pragma unroll
    for (int u = 0; u < 8; ++u) {
        const int fidx = base + u;
        int nf = fidx + 1;
        if (nf == B_DIM * S_DIM) nf = 0;   // torch .roll on flattened tensor wraps globally
        const float P0 = p0[fidx];
        const float sp = p1[nf];
        const float pr = prior[fidx];
        const float na = pr + (1.f - pr) * sqrtf(P0 * sp + 1e-6f);
        out_na[fidx] = na;
        run += __logf(na);
        incl[u] = run;
    }
    sh[tid] = run;
    __syncthreads();
    // inclusive Hillis-Steele scan over 256 thread totals
    for (int off = 1; off < 256; off <<= 1) {
        float v = sh[tid];
        if (tid >= off) v += sh[tid - off];
        __syncthreads();
        sh[tid] = v;
        __syncthreads();
    }
    const float offset = (tid > 0) ? sh[tid - 1] : 0.f;
#pragma unroll
    for (int u = 0; u < 8; ++u) {
        cs[base + u] = offset + ((u > 0) ? incl[u - 1] : 0.f);  // exclusive prefix
    }
}

// ---------------- K4: big output C[b,i,j] = exp(sign*(cs[j]-cs[i])), 0 on diag ----------------
__global__ __launch_bounds__(256) void big_out(const float* __restrict__ cs,
                                               float* __restrict__ out) {
    const int bi = blockIdx.x;          // b*S + i
    const int b = bi >> 11;             // / S_DIM
    const int i = bi & (S_DIM - 1);
    const float ci = cs[b * S_DIM + i];
    const float* crow = cs + (size_t)b * S_DIM;
    float* orow = out + (size_t)bi * S_DIM;
    const int j0 = threadIdx.x * 8;
#pragma unroll
    for (int h = 0; h < 2; ++h) {
        const int j = j0 + h * 4;
        const float4 cj = *(const float4*)&crow[j];
        float4 o;
        {
            const int jj = j + 0; const float m = (jj > i) ? (cj.x - ci) : (ci - cj.x);
            o.x = (jj == i) ? 0.f : __expf(m);
        }
        {
            const int jj = j + 1; const float m = (jj > i) ? (cj.y - ci) : (ci - cj.y);
            o.y = (jj == i) ? 0.f : __expf(m);
        }
        {
            const int jj = j + 2; const float m = (jj > i) ? (cj.z - ci) : (ci - cj.z);
            o.z = (jj == i) ? 0.f : __expf(m);
        }
        {
            const int jj = j + 3; const float m = (jj > i) ? (cj.w - ci) : (ci - cj.w);
            o.w = (jj == i) ? 0.f : __expf(m);
        }
        *(float4*)&orow[j] = o;
    }
}

extern "C" void kernel_launch(void* const* d_in, const int* in_sizes, int n_in,
                              void* d_out, int out_size, void* d_ws, size_t ws_size,
                              hipStream_t stream) {
    const float* context = (const float*)d_in[0];   // (S,B,E) fp32
    const float* prior   = (const float*)d_in[1];   // (B,S) fp32
    const float* W       = (const float*)d_in[2];   // (128,1024) fp32
    const float* bias    = (const float*)d_in[3];   // (128,) fp32
    float* out = (float*)d_out;

    float* qk = (float*)d_ws;                          // 16384*128 floats
    float* p0 = qk + (size_t)M_TOT * NP;               // 16384 floats
    float* p1 = p0 + M_TOT;                            // 16384 floats
    float* cs = p1 + M_TOT;                            // 16384 floats
    float* na_out = out + (size_t)B_DIM * S_DIM * S_DIM;  // second output

    gemm_qk<<<M_TOT / BM, 256, 0, stream>>>(context, W, bias, qk);
    neighbor_probs<<<M_TOT / 4, 256, 0, stream>>>(qk, p0, p1);
    combine_scan<<<B_DIM, 256, 0, stream>>>(p0, p1, prior, na_out, cs);
    big_out<<<M_TOT, 256, 0, stream>>>(cs, out);
}

// Round 2
// 108.052 us; speedup vs baseline: 1.0704x; 1.0704x over previous
//
#include <hip/hip_runtime.h>
#include <cstdint>
#include <cstddef>

#define E_DIM 1024
#define PD 64            // proj dim
#define NP 128           // 2*proj dim
#define B_DIM 8
#define S_DIM 2048
#define M_TOT (B_DIM * S_DIM)   // 16384

// ---------------- K1: GEMM qk[m][p] = sum_k A[m][k] * W[p][k] + bias[p] ----------------
// A is context viewed as (S*B, E) row-major; row m = s*B + b.
// BM=32 -> grid 512 (2 blocks/CU, 8 waves/CU). 256 threads, 4x4 acc/thread.
// LDS double-buffered, register-staged prefetch (1 barrier per K-chunk).
#define BM 32
#define BK 32
#define SA 36    // BM + 4 pad (16B-aligned rows, conflict-light transposed stores)
#define SB 132   // NP + 4 pad

__global__ __launch_bounds__(256, 2) void gemm_qk(const float* __restrict__ A,
                                                  const float* __restrict__ W,
                                                  const float* __restrict__ bias,
                                                  float* __restrict__ qk) {
    __shared__ float As[2][BK][SA];
    __shared__ float Bs[2][BK][SB];
    const int tid = threadIdx.x;
    const int m0 = blockIdx.x * BM;
    const int ty = tid >> 5;      // 0..7  -> output rows ty*4..+3
    const int tx = tid & 31;      // 0..31 -> output cols tx*4..+3
    const int srow = tid >> 3;    // 0..31 staging row
    const int sk = (tid & 7) * 4; // staging k offset (coalesced along K)

    const float* aptr = A + (size_t)(m0 + srow) * E_DIM + sk;
    const float* wptr = W + (size_t)srow * E_DIM + sk;

    float acc[4][4];
#pragma unroll
    for (int r = 0; r < 4; ++r)
#pragma unroll
        for (int c = 0; c < 4; ++c) acc[r][c] = 0.f;

    // prologue: stage chunk 0
    float4 ra  = *(const float4*)(aptr);
    float4 rw0 = *(const float4*)(wptr);
    float4 rw1 = *(const float4*)(wptr + 32 * E_DIM);
    float4 rw2 = *(const float4*)(wptr + 64 * E_DIM);
    float4 rw3 = *(const float4*)(wptr + 96 * E_DIM);
    {
        const float av[4] = {ra.x, ra.y, ra.z, ra.w};
        const float w0[4] = {rw0.x, rw0.y, rw0.z, rw0.w};
        const float w1[4] = {rw1.x, rw1.y, rw1.z, rw1.w};
        const float w2[4] = {rw2.x, rw2.y, rw2.z, rw2.w};
        const float w3[4] = {rw3.x, rw3.y, rw3.z, rw3.w};
#pragma unroll
        for (int i = 0; i < 4; ++i) {
            As[0][sk + i][srow] = av[i];
            Bs[0][sk + i][srow]      = w0[i];
            Bs[0][sk + i][srow + 32] = w1[i];
            Bs[0][sk + i][srow + 64] = w2[i];
            Bs[0][sk + i][srow + 96] = w3[i];
        }
    }

    const int NCHUNK = E_DIM / BK;  // 32
    for (int kc = 0; kc < NCHUNK; ++kc) {
        const int buf = kc & 1;
        __syncthreads();
        if (kc + 1 < NCHUNK) {
            const int off = (kc + 1) * BK;
            ra  = *(const float4*)(aptr + off);
            rw0 = *(const float4*)(wptr + off);
            rw1 = *(const float4*)(wptr + off + 32 * E_DIM);
            rw2 = *(const float4*)(wptr + off + 64 * E_DIM);
            rw3 = *(const float4*)(wptr + off + 96 * E_DIM);
        }
#pragma unroll 8
        for (int k = 0; k < BK; ++k) {
            const float4 av4 = *(const float4*)&As[buf][k][ty * 4];
            const float4 bv4 = *(const float4*)&Bs[buf][k][tx * 4];
            const float av[4] = {av4.x, av4.y, av4.z, av4.w};
            const float bv[4] = {bv4.x, bv4.y, bv4.z, bv4.w};
#pragma unroll
            for (int r = 0; r < 4; ++r)
#pragma unroll
                for (int c = 0; c < 4; ++c) acc[r][c] += av[r] * bv[c];
        }
        if (kc + 1 < NCHUNK) {
            const int nb = buf ^ 1;
            const float av[4] = {ra.x, ra.y, ra.z, ra.w};
            const float w0[4] = {rw0.x, rw0.y, rw0.z, rw0.w};
            const float w1[4] = {rw1.x, rw1.y, rw1.z, rw1.w};
            const float w2[4] = {rw2.x, rw2.y, rw2.z, rw2.w};
            const float w3[4] = {rw3.x, rw3.y, rw3.z, rw3.w};
#pragma unroll
            for (int i = 0; i < 4; ++i) {
                As[nb][sk + i][srow] = av[i];
                Bs[nb][sk + i][srow]      = w0[i];
                Bs[nb][sk + i][srow + 32] = w1[i];
                Bs[nb][sk + i][srow + 64] = w2[i];
                Bs[nb][sk + i][srow + 96] = w3[i];
            }
        }
    }

    const float4 bv4 = *(const float4*)&bias[tx * 4];
#pragma unroll
    for (int r = 0; r < 4; ++r) {
        const size_t m = (size_t)m0 + ty * 4 + r;
        float4 o;
        o.x = acc[r][0] + bv4.x;
        o.y = acc[r][1] + bv4.y;
        o.z = acc[r][2] + bv4.z;
        o.w = acc[r][3] + bv4.w;
        *(float4*)&qk[m * NP + tx * 4] = o;
    }
}

// ---------------- K2: neighbor scores + 2-way softmax -> p0,p1 (indexed b*S+s) ----------------
__global__ __launch_bounds__(256) void neighbor_probs(const float* __restrict__ qk,
                                                      float* __restrict__ p0,
                                                      float* __restrict__ p1) {
    const int wid = blockIdx.x * 4 + (threadIdx.x >> 6);  // position index m = s*B+b
    const int lane = threadIdx.x & 63;
    const int m = wid;
    const int s = m >> 3;   // / B_DIM
    const int b = m & 7;    // % B_DIM

    const float q = qk[(size_t)m * NP + lane];
    const float kn = (s < S_DIM - 1) ? qk[(size_t)(m + B_DIM) * NP + PD + lane] : 0.f;
    const float kp = (s > 0) ? qk[(size_t)(m - B_DIM) * NP + PD + lane] : 0.f;
    float f = q * kn;   // fwd partial: query[s] . key[s+1]
    float g = q * kp;   // bwd partial: query[s] . key[s-1]
#pragma unroll
    for (int off = 32; off; off >>= 1) {
        f += __shfl_xor(f, off);
        g += __shfl_xor(g, off);
    }
    if (lane == 0) {
        const float s0 = f * (1.f / (float)E_DIM);
        const float s1 = g * (1.f / (float)E_DIM);
        float P0, P1;
        if (s == S_DIM - 1) { P0 = 0.f; P1 = 1.f; }
        else if (s == 0)    { P0 = 1.f; P1 = 0.f; }
        else {
            const float mx = fmaxf(s0, s1);
            const float e0 = __expf(s0 - mx), e1 = __expf(s1 - mx);
            const float inv = 1.f / (e0 + e1);
            P0 = e0 * inv; P1 = e1 * inv;
        }
        p0[b * S_DIM + s] = P0;
        p1[b * S_DIM + s] = P1;
    }
}

// ---------------- K3: combine (with flat roll), neighbor_attn out, log, exclusive scan ----------------
__global__ __launch_bounds__(256) void combine_scan(const float* __restrict__ p0,
                                                    const float* __restrict__ p1,
                                                    const float* __restrict__ prior,
                                                    float* __restrict__ out_na,
                                                    float* __restrict__ cs) {
    const int b = blockIdx.x;
    const int tid = threadIdx.x;
    __shared__ float sh[256];

    const int base = b * S_DIM + tid * 8;
    float incl[8];
    float run = 0.f;
#pragma unroll
    for (int u = 0; u < 8; ++u) {
        const int fidx = base + u;
        int nf = fidx + 1;
        if (nf == B_DIM * S_DIM) nf = 0;   // torch .roll on flattened tensor wraps globally
        const float P0 = p0[fidx];
        const float sp = p1[nf];
        const float pr = prior[fidx];
        const float na = pr + (1.f - pr) * sqrtf(P0 * sp + 1e-6f);
        out_na[fidx] = na;
        run += __logf(na);
        incl[u] = run;
    }
    sh[tid] = run;
    __syncthreads();
    // inclusive Hillis-Steele scan over 256 thread totals
    for (int off = 1; off < 256; off <<= 1) {
        float v = sh[tid];
        if (tid >= off) v += sh[tid - off];
        __syncthreads();
        sh[tid] = v;
        __syncthreads();
    }
    const float offset = (tid > 0) ? sh[tid - 1] : 0.f;
#pragma unroll
    for (int u = 0; u < 8; ++u) {
        cs[base + u] = offset + ((u > 0) ? incl[u - 1] : 0.f);  // exclusive prefix
    }
}

// ---------------- K4: big output C[b,i,j] = exp(sign*(cs[j]-cs[i])), 0 on diag ----------------
__global__ __launch_bounds__(256) void big_out(const float* __restrict__ cs,
                                               float* __restrict__ out) {
    const int bi = blockIdx.x;          // b*S + i
    const int b = bi >> 11;             // / S_DIM
    const int i = bi & (S_DIM - 1);
    const float ci = cs[b * S_DIM + i];
    const float* crow = cs + (size_t)b * S_DIM;
    float* orow = out + (size_t)bi * S_DIM;
    const int j0 = threadIdx.x * 8;
#pragma unroll
    for (int h = 0; h < 2; ++h) {
        const int j = j0 + h * 4;
        const float4 cj = *(const float4*)&crow[j];
        float4 o;
        {
            const int jj = j + 0; const float m = (jj > i) ? (cj.x - ci) : (ci - cj.x);
            o.x = (jj == i) ? 0.f : __expf(m);
        }
        {
            const int jj = j + 1; const float m = (jj > i) ? (cj.y - ci) : (ci - cj.y);
            o.y = (jj == i) ? 0.f : __expf(m);
        }
        {
            const int jj = j + 2; const float m = (jj > i) ? (cj.z - ci) : (ci - cj.z);
            o.z = (jj == i) ? 0.f : __expf(m);
        }
        {
            const int jj = j + 3; const float m = (jj > i) ? (cj.w - ci) : (ci - cj.w);
            o.w = (jj == i) ? 0.f : __expf(m);
        }
        *(float4*)&orow[j] = o;
    }
}

extern "C" void kernel_launch(void* const* d_in, const int* in_sizes, int n_in,
                              void* d_out, int out_size, void* d_ws, size_t ws_size,
                              hipStream_t stream) {
    const float* context = (const float*)d_in[0];   // (S,B,E) fp32
    const float* prior   = (const float*)d_in[1];   // (B,S) fp32
    const float* W       = (const float*)d_in[2];   // (128,1024) fp32
    const float* bias    = (const float*)d_in[3];   // (128,) fp32
    float* out = (float*)d_out;

    float* qk = (float*)d_ws;                          // 16384*128 floats
    float* p0 = qk + (size_t)M_TOT * NP;               // 16384 floats
    float* p1 = p0 + M_TOT;                            // 16384 floats
    float* cs = p1 + M_TOT;                            // 16384 floats
    float* na_out = out + (size_t)B_DIM * S_DIM * S_DIM;  // second output

    gemm_qk<<<M_TOT / BM, 256, 0, stream>>>(context, W, bias, qk);
    neighbor_probs<<<M_TOT / 4, 256, 0, stream>>>(qk, p0, p1);
    combine_scan<<<B_DIM, 256, 0, stream>>>(p0, p1, prior, na_out, cs);
    big_out<<<M_TOT, 256, 0, stream>>>(cs, out);
}